// Round 8
// baseline (246.592 us; speedup 1.0000x reference)
//
#include <hip/hip_runtime.h>
#include <hip/hip_bf16.h>
#include <stdint.h>

typedef __attribute__((ext_vector_type(8))) short short8;
typedef __attribute__((ext_vector_type(4))) float f32x4;

__device__ __forceinline__ short f2bf(float f) {
  __hip_bfloat16 h = __float2bfloat16(f);  // RNE
  union { __hip_bfloat16 h; unsigned short u; } c;
  c.h = h;
  return (short)c.u;
}
__device__ __forceinline__ short8 cvt8(const float* p) {
  const float4 f0 = *(const float4*)p;
  const float4 f1 = *(const float4*)(p + 4);
  short8 r;
  r[0] = f2bf(f0.x); r[1] = f2bf(f0.y); r[2] = f2bf(f0.z); r[3] = f2bf(f0.w);
  r[4] = f2bf(f1.x); r[5] = f2bf(f1.y); r[6] = f2bf(f1.z); r[7] = f2bf(f1.w);
  return r;
}

// packed weights in d_ws (bf16 in shorts), page = 512 shorts = 1KB:
//   Win : pages   0..191  : (t*8+K0)*8+nf          [3][8K0][8nf]
//   Wh  : pages 192..383  : 192+((t*2+L)*4+ks)*8+nf [3][2][4ks][8nf]
//   Wout: pages 384..575  : 384+(t*4+K0)*16+nf16    [3][4K0][16nf]
// Consumption order per tower = contiguous 16-page (16KB) chunks.
__global__ __launch_bounds__(256) void pack_weights(
    const float* __restrict__ Win, const float* __restrict__ Wh,
    const float* __restrict__ Wout, short* __restrict__ o) {
  int gid = blockIdx.x * 256 + threadIdx.x;
  if (gid < 12288) {
    int t = gid / 4096, r = gid % 4096;
    int ks = r / 512, r2 = r % 512, nf = r2 / 64, l = r2 % 64;
    int n = nf * 16 + (l & 15);
    int kb = ks * 32 + (l >> 4) * 8;
#pragma unroll
    for (int i = 0; i < 8; ++i)
      o[gid * 8 + i] = f2bf(Win[(t * 256 + kb + i) * 128 + n]);
  } else if (gid < 24576) {
    int h = gid - 12288;
    int tl = h / 2048, r = h % 2048;
    int ks = r / 512, nf = (r % 512) / 64, l = r % 64;
    int n = nf * 16 + (l & 15);
    int kb = ks * 32 + (l >> 4) * 8;
#pragma unroll
    for (int i = 0; i < 8; ++i)
      o[98304 + h * 8 + i] = f2bf(Wh[(tl * 128 + kb + i) * 128 + n]);
  } else {
    int oo = gid - 24576;
    int t = oo / 4096, r = oo % 4096;
    int ks = r / 1024, nf = (r % 1024) / 64, l = r % 64;
    int n = nf * 16 + (l & 15);
    int kb = ks * 32 + (l >> 4) * 8;
#pragma unroll
    for (int i = 0; i < 8; ++i)
      o[196608 + oo * 8 + i] = f2bf(Wout[(t * 128 + kb + i) * 256 + n]);
  }
}

// async-stage one 16KB chunk (16 pages) into LDS: linear copy, 4 rounds.
__device__ __forceinline__ void stage16k(const short* __restrict__ wp,
                                         char* lbuf, int pageBase, int tid) {
  const char* g = (const char*)wp + (size_t)pageBase * 1024 + (size_t)tid * 16;
  char* l = lbuf + (tid >> 6) * 1024;  // wave-uniform base; HW adds lane*16
#pragma unroll
  for (int r = 0; r < 4; ++r) {
    __builtin_amdgcn_global_load_lds(
        (const __attribute__((address_space(1))) void*)(g + r * 4096),
        (__attribute__((address_space(3))) void*)(l + r * 4096), 16, 0, 0);
  }
}

// 256 threads / 4 waves / 64 rows per block. Towers sequential; weights
// double-buffered via global_load_lds (stage i+1 before compute i; the
// __syncthreads vmcnt-drain is the phase boundary). B always from LDS.
__global__ __launch_bounds__(256, 2) void fused_towers(
    const int* __restrict__ user, const int* __restrict__ item,
    const float* __restrict__ su, const float* __restrict__ ti,
    const float* __restrict__ bin, const float* __restrict__ bh,
    const float* __restrict__ bout, const short* __restrict__ wp,
    float* __restrict__ out) {
  __shared__ __align__(16) char WB[2][16384];  // weight chunk double-buffer
  __shared__ __align__(16) char Act[16384];    // 64 rows x 256B, XOR-swizzled
  __shared__ float sL[3][64];
  __shared__ float sS[3][64];
  __shared__ int sUid[64];
  __shared__ int sItm[64];

  const int tid = threadIdx.x;
  const int w = tid >> 6, lane = tid & 63;
  const int ar = lane & 15, g = lane >> 4;
  const int swzA = (ar & 7) << 4;
  const f32x4 fz = {0.f, 0.f, 0.f, 0.f};

  if (tid < 64) {
    sUid[tid] = user[blockIdx.x * 64 + tid];
    sItm[tid] = item[blockIdx.x * 64 + tid];
  }
  if (tid < 192) { (&sL[0][0])[tid] = 0.f; (&sS[0][0])[tid] = 0.f; }
  stage16k(wp, WB[0], 0, tid);  // tower0 L1c0
  __syncthreads();
  int cur = 0;

  for (int t = 0; t < 3; ++t) {
    // chunk page-base schedule for this tower
    const int b1 = t * 64;
    const int b2 = 192 + (t * 2) * 32;
    const int b3 = 192 + (t * 2 + 1) * 32;
    const int b4 = 384 + t * 64;
    const float* up[4];
#pragma unroll
    for (int m = 0; m < 4; ++m) up[m] = su + (size_t)sUid[m * 16 + ar] * 256;

    f32x4 acc[4][2];
    // ---------- L1: [64x256] @ [256x128] -> Act, 4 chunks ----------
#pragma unroll
    for (int m = 0; m < 4; ++m) { acc[m][0] = fz; acc[m][1] = fz; }
    for (int c = 0; c < 4; ++c) {
      stage16k(wp, WB[cur ^ 1], (c < 3) ? (b1 + (c + 1) * 16) : b2, tid);
      const char* wb = WB[cur];
#pragma unroll
      for (int ksl = 0; ksl < 2; ++ksl) {
        const int K0 = c * 2 + ksl;
        short8 a[4];
#pragma unroll
        for (int m = 0; m < 4; ++m) a[m] = cvt8(up[m] + K0 * 32 + g * 8);
#pragma unroll
        for (int nfl = 0; nfl < 2; ++nfl) {
          const short8 b = *(const short8*)(wb + (ksl * 8 + w * 2 + nfl) * 1024 + lane * 16);
#pragma unroll
          for (int m = 0; m < 4; ++m)
            acc[m][nfl] = __builtin_amdgcn_mfma_f32_16x16x32_bf16(a[m], b, acc[m][nfl], 0, 0, 0);
        }
      }
      __syncthreads();
      cur ^= 1;
    }
#pragma unroll
    for (int m = 0; m < 4; ++m)
#pragma unroll
      for (int nfl = 0; nfl < 2; ++nfl) {
        const int col = w * 32 + nfl * 16 + ar;
        const float bv = bin[t * 128 + col];
#pragma unroll
        for (int q = 0; q < 4; ++q) {
          const int r = m * 16 + g * 4 + q;
          const float v = fmaxf(acc[m][nfl][q] + bv, 0.f);
          *(short*)(Act + r * 256 + ((col * 2) ^ ((r & 7) << 4))) = f2bf(v);
        }
      }
    __syncthreads();

    // ---------- L2, L3: [64x128] @ [128x128], in-place, 2 chunks each ----------
#pragma unroll
    for (int L = 0; L < 2; ++L) {
      const int bb = L ? b3 : b2;
      const int nx0 = L ? b4 : b3;
#pragma unroll
      for (int m = 0; m < 4; ++m) { acc[m][0] = fz; acc[m][1] = fz; }
      for (int c = 0; c < 2; ++c) {
        stage16k(wp, WB[cur ^ 1], (c < 1) ? (bb + 16) : nx0, tid);
        const char* wb = WB[cur];
#pragma unroll
        for (int csl = 0; csl < 2; ++csl) {
          const int ks = c * 2 + csl;
          short8 a[4];
#pragma unroll
          for (int m = 0; m < 4; ++m) {
            const int r = m * 16 + ar;
            a[m] = *(const short8*)(Act + r * 256 + ((ks * 64 + g * 16) ^ swzA));
          }
#pragma unroll
          for (int nfl = 0; nfl < 2; ++nfl) {
            const short8 b = *(const short8*)(wb + (csl * 8 + w * 2 + nfl) * 1024 + lane * 16);
#pragma unroll
            for (int m = 0; m < 4; ++m)
              acc[m][nfl] = __builtin_amdgcn_mfma_f32_16x16x32_bf16(a[m], b, acc[m][nfl], 0, 0, 0);
          }
        }
        __syncthreads();
        cur ^= 1;
      }
#pragma unroll
      for (int m = 0; m < 4; ++m)
#pragma unroll
        for (int nfl = 0; nfl < 2; ++nfl) {
          const int col = w * 32 + nfl * 16 + ar;
          const float bv = bh[(t * 2 + L) * 128 + col];
#pragma unroll
          for (int q = 0; q < 4; ++q) {
            const int r = m * 16 + g * 4 + q;
            const float v = fmaxf(acc[m][nfl][q] + bv, 0.f);
            *(short*)(Act + r * 256 + ((col * 2) ^ ((r & 7) << 4))) = f2bf(v);
          }
        }
      __syncthreads();
    }

    // ---------- L4: [64x128] @ [128x256], 4 chunks (chunk = K0) ----------
    f32x4 acc4[4][4];
#pragma unroll
    for (int m = 0; m < 4; ++m)
#pragma unroll
      for (int n = 0; n < 4; ++n) acc4[m][n] = fz;
    for (int c = 0; c < 4; ++c) {
      const bool last = (t == 2) && (c == 3);
      if (!last)
        stage16k(wp, WB[cur ^ 1], (c < 3) ? (b4 + (c + 1) * 16) : ((t + 1) * 64), tid);
      const char* wb = WB[cur];
      short8 a4[4];
#pragma unroll
      for (int m = 0; m < 4; ++m) {
        const int r = m * 16 + ar;
        a4[m] = *(const short8*)(Act + r * 256 + ((c * 64 + g * 16) ^ swzA));
      }
#pragma unroll
      for (int nfl = 0; nfl < 4; ++nfl) {
        const short8 b = *(const short8*)(wb + (w * 4 + nfl) * 1024 + lane * 16);
#pragma unroll
        for (int m = 0; m < 4; ++m)
          acc4[m][nfl] = __builtin_amdgcn_mfma_f32_16x16x32_bf16(a4[m], b, acc4[m][nfl], 0, 0, 0);
      }
      __syncthreads();
      cur ^= 1;
    }

    // ---------- tail: fp32 logits/scores straight from acc4 ----------
    float pl[16], ps[16];
#pragma unroll
    for (int i = 0; i < 16; ++i) { pl[i] = 0.f; ps[i] = 0.f; }
#pragma unroll
    for (int m = 0; m < 4; ++m)
#pragma unroll
      for (int nfl = 0; nfl < 4; ++nfl) {
        const int col = w * 64 + nfl * 16 + ar;
        const float bo = bout[t * 256 + col];
#pragma unroll
        for (int q = 0; q < 4; ++q) {
          const int r = m * 16 + g * 4 + q;
          const float x = acc4[m][nfl][q] + bo;
          const float kv = ti[(size_t)sUid[r] * 256 + col];
          const float ev = ti[(size_t)sItm[r] * 256 + col];
          pl[m * 4 + q] += x * kv;
          ps[m * 4 + q] += x * ev;
        }
      }
#pragma unroll
    for (int i = 0; i < 16; ++i) {
      float a0 = pl[i], b0 = ps[i];
#pragma unroll
      for (int off = 1; off < 16; off <<= 1) {
        a0 += __shfl_xor(a0, off);
        b0 += __shfl_xor(b0, off);
      }
      pl[i] = a0; ps[i] = b0;
    }
    if (ar == 0) {
#pragma unroll
      for (int m = 0; m < 4; ++m)
#pragma unroll
        for (int q = 0; q < 4; ++q) {
          const int r = m * 16 + g * 4 + q;
          atomicAdd(&sL[t][r], pl[m * 4 + q]);
          atomicAdd(&sS[t][r], ps[m * 4 + q]);
        }
    }
  }
  __syncthreads();

  if (tid < 64) {
    const float l0 = sL[0][tid], l1 = sL[1][tid], l2 = sL[2][tid];
    const float mx = fmaxf(l0, fmaxf(l1, l2));
    const float e0 = __expf(l0 - mx), e1 = __expf(l1 - mx), e2 = __expf(l2 - mx);
    out[blockIdx.x * 64 + tid] =
        (e0 * sS[0][tid] + e1 * sS[1][tid] + e2 * sS[2][tid]) / (e0 + e1 + e2);
  }
}

extern "C" void kernel_launch(void* const* d_in, const int* in_sizes, int n_in,
                              void* d_out, int out_size, void* d_ws, size_t ws_size,
                              hipStream_t stream) {
  const int* user = (const int*)d_in[0];
  const int* item = (const int*)d_in[1];
  const float* su = (const float*)d_in[2];
  const float* ti = (const float*)d_in[3];
  const float* Win = (const float*)d_in[4];
  const float* bin = (const float*)d_in[5];
  const float* Wh = (const float*)d_in[6];
  const float* bh = (const float*)d_in[7];
  const float* Wout = (const float*)d_in[8];
  const float* bout = (const float*)d_in[9];
  float* out = (float*)d_out;
  short* ws = (short*)d_ws;

  hipLaunchKernelGGL(pack_weights, dim3(144), dim3(256), 0, stream, Win, Wh, Wout, ws);
  hipLaunchKernelGGL(fused_towers, dim3(1024), dim3(256), 0, stream,
                     user, item, su, ti, bin, bh, bout, (const short*)ws, out);
}

// Round 9
// 204.660 us; speedup vs baseline: 1.2049x; 1.2049x over previous
//
#include <hip/hip_runtime.h>
#include <hip/hip_bf16.h>
#include <stdint.h>

typedef __attribute__((ext_vector_type(8))) short short8;
typedef __attribute__((ext_vector_type(4))) float f32x4;

__device__ __forceinline__ short f2bf(float f) {
  __hip_bfloat16 h = __float2bfloat16(f);  // RNE
  union { __hip_bfloat16 h; unsigned short u; } c;
  c.h = h;
  return (short)c.u;
}
__device__ __forceinline__ short8 cvt8(const float* p) {
  const float4 f0 = *(const float4*)p;
  const float4 f1 = *(const float4*)(p + 4);
  short8 r;
  r[0] = f2bf(f0.x); r[1] = f2bf(f0.y); r[2] = f2bf(f0.z); r[3] = f2bf(f0.w);
  r[4] = f2bf(f1.x); r[5] = f2bf(f1.y); r[6] = f2bf(f1.z); r[7] = f2bf(f1.w);
  return r;
}

// packed weights (bf16 in shorts), page = 512 shorts = 1KB:
//   Win : pages   0..191 : t*64 + K0*8 + nf            [3][8K0][8nf]
//   Wh  : pages 192..383 : 192 + t*64 + L*32 + ks*8+nf [3][2L][4ks][8nf]
//   Wout: pages 384..575 : 384 + t*64 + K0*16 + nf     [3][4K0][16nf]
__global__ __launch_bounds__(256) void pack_weights(
    const float* __restrict__ Win, const float* __restrict__ Wh,
    const float* __restrict__ Wout, short* __restrict__ o) {
  int gid = blockIdx.x * 256 + threadIdx.x;
  if (gid < 12288) {
    int t = gid / 4096, r = gid % 4096;
    int ks = r / 512, r2 = r % 512, nf = r2 / 64, l = r2 % 64;
    int n = nf * 16 + (l & 15);
    int kb = ks * 32 + (l >> 4) * 8;
#pragma unroll
    for (int i = 0; i < 8; ++i)
      o[gid * 8 + i] = f2bf(Win[(t * 256 + kb + i) * 128 + n]);
  } else if (gid < 24576) {
    int h = gid - 12288;
    int tl = h / 2048, r = h % 2048;
    int ks = r / 512, nf = (r % 512) / 64, l = r % 64;
    int n = nf * 16 + (l & 15);
    int kb = ks * 32 + (l >> 4) * 8;
#pragma unroll
    for (int i = 0; i < 8; ++i)
      o[98304 + h * 8 + i] = f2bf(Wh[(tl * 128 + kb + i) * 128 + n]);
  } else {
    int oo = gid - 24576;
    int t = oo / 4096, r = oo % 4096;
    int ks = r / 1024, nf = (r % 1024) / 64, l = r % 64;
    int n = nf * 16 + (l & 15);
    int kb = ks * 32 + (l >> 4) * 8;
#pragma unroll
    for (int i = 0; i < 8; ++i)
      o[196608 + oo * 8 + i] = f2bf(Wout[(t * 128 + kb + i) * 256 + n]);
  }
}

// async-stage `rounds` x 4KB into LDS (linear, 256 threads).
__device__ __forceinline__ void stageN(const short* __restrict__ wp, char* lbuf,
                                       int pageBase, int tid, int rounds) {
  const char* g = (const char*)wp + (size_t)pageBase * 1024 + (size_t)tid * 16;
  char* l = lbuf + (tid >> 6) * 1024;  // wave-uniform base; HW adds lane*16
  for (int r = 0; r < rounds; ++r) {
    __builtin_amdgcn_global_load_lds(
        (const __attribute__((address_space(1))) void*)(g + r * 4096),
        (__attribute__((address_space(3))) void*)(l + r * 4096), 16, 0, 0);
  }
}

// ---- K0: U[row][256] = bf16(su[user[row]]) ----
__global__ __launch_bounds__(256) void k_gather_u(
    const int* __restrict__ user, const float* __restrict__ su,
    short* __restrict__ U, int nrows) {
  const int idx = blockIdx.x * 256 + threadIdx.x;
  const int row = idx >> 5, c = idx & 31;
  const int uid = user[row];
  *(short8*)(U + (size_t)row * 256 + c * 8) = cvt8(su + (size_t)uid * 256 + c * 8);
}

// ---- K1: L1 per (tower, 128-row block): U @ Win_t -> H1_t ----
__global__ __launch_bounds__(256, 2) void k_l1(
    const short* __restrict__ U, const float* __restrict__ bin,
    const short* __restrict__ wp, short* __restrict__ H1, int nrows) {
  __shared__ __align__(16) char sB[65536];
  const int tid = threadIdx.x, w = tid >> 6, lane = tid & 63;
  const int ar = lane & 15, g = lane >> 4;
  const int t = blockIdx.y;
  const int rblk = blockIdx.x * 128;
  const f32x4 fz = {0.f, 0.f, 0.f, 0.f};

  stageN(wp, sB, t * 64, tid, 16);  // Win_t, 64KB, once
  __syncthreads();

  f32x4 acc[8][2];
#pragma unroll
  for (int m = 0; m < 8; ++m) { acc[m][0] = fz; acc[m][1] = fz; }
#pragma unroll
  for (int K0 = 0; K0 < 8; ++K0) {
    short8 a[8];
#pragma unroll
    for (int m = 0; m < 8; ++m)
      a[m] = *(const short8*)(U + (size_t)(rblk + m * 16 + ar) * 256 + K0 * 32 + g * 8);
#pragma unroll
    for (int nfl = 0; nfl < 2; ++nfl) {
      const short8 b = *(const short8*)(sB + (K0 * 8 + w * 2 + nfl) * 1024 + lane * 16);
#pragma unroll
      for (int m = 0; m < 8; ++m)
        acc[m][nfl] = __builtin_amdgcn_mfma_f32_16x16x32_bf16(a[m], b, acc[m][nfl], 0, 0, 0);
    }
  }
#pragma unroll
  for (int m = 0; m < 8; ++m)
#pragma unroll
    for (int nfl = 0; nfl < 2; ++nfl) {
      const int col = w * 32 + nfl * 16 + ar;
      const float bv = bin[t * 128 + col];
#pragma unroll
      for (int q = 0; q < 4; ++q) {
        const int r = rblk + m * 16 + g * 4 + q;
        H1[((size_t)t * nrows + r) * 128 + col] = f2bf(fmaxf(acc[m][nfl][q] + bv, 0.f));
      }
    }
}

// ---- K2: L2+L3 per (tower, 64-row block): H1 -> H3 ----
__global__ __launch_bounds__(256, 2) void k_l23(
    const short* __restrict__ H1, const float* __restrict__ bh,
    const short* __restrict__ wp, short* __restrict__ H3, int nrows) {
  __shared__ __align__(16) char sB[65536];
  __shared__ __align__(16) char H2[16384];
  const int tid = threadIdx.x, w = tid >> 6, lane = tid & 63;
  const int ar = lane & 15, g = lane >> 4;
  const int t = blockIdx.y;
  const int rblk = blockIdx.x * 64;
  const int swzA = (ar & 7) << 4;
  const f32x4 fz = {0.f, 0.f, 0.f, 0.f};

  stageN(wp, sB, 192 + t * 64, tid, 16);  // Wh_t (both layers), 64KB, once
  __syncthreads();

  // L2: A from H1 (global), out -> H2 (LDS, swizzled)
  f32x4 acc[4][2];
#pragma unroll
  for (int m = 0; m < 4; ++m) { acc[m][0] = fz; acc[m][1] = fz; }
#pragma unroll
  for (int ks = 0; ks < 4; ++ks) {
    short8 a[4];
#pragma unroll
    for (int m = 0; m < 4; ++m)
      a[m] = *(const short8*)(H1 + ((size_t)t * nrows + rblk + m * 16 + ar) * 128 + ks * 32 + g * 8);
#pragma unroll
    for (int nfl = 0; nfl < 2; ++nfl) {
      const short8 b = *(const short8*)(sB + (ks * 8 + w * 2 + nfl) * 1024 + lane * 16);
#pragma unroll
      for (int m = 0; m < 4; ++m)
        acc[m][nfl] = __builtin_amdgcn_mfma_f32_16x16x32_bf16(a[m], b, acc[m][nfl], 0, 0, 0);
    }
  }
#pragma unroll
  for (int m = 0; m < 4; ++m)
#pragma unroll
    for (int nfl = 0; nfl < 2; ++nfl) {
      const int col = w * 32 + nfl * 16 + ar;
      const float bv = bh[(t * 2) * 128 + col];
#pragma unroll
      for (int q = 0; q < 4; ++q) {
        const int r = m * 16 + g * 4 + q;
        *(short*)(H2 + r * 256 + ((col * 2) ^ ((r & 7) << 4))) =
            f2bf(fmaxf(acc[m][nfl][q] + bv, 0.f));
      }
    }
  __syncthreads();

  // L3: A from H2 (LDS), out -> H3 (global)
#pragma unroll
  for (int m = 0; m < 4; ++m) { acc[m][0] = fz; acc[m][1] = fz; }
#pragma unroll
  for (int ks = 0; ks < 4; ++ks) {
    short8 a[4];
#pragma unroll
    for (int m = 0; m < 4; ++m)
      a[m] = *(const short8*)(H2 + (m * 16 + ar) * 256 + ((ks * 64 + g * 16) ^ swzA));
#pragma unroll
    for (int nfl = 0; nfl < 2; ++nfl) {
      const short8 b = *(const short8*)(sB + (32 + ks * 8 + w * 2 + nfl) * 1024 + lane * 16);
#pragma unroll
      for (int m = 0; m < 4; ++m)
        acc[m][nfl] = __builtin_amdgcn_mfma_f32_16x16x32_bf16(a[m], b, acc[m][nfl], 0, 0, 0);
    }
  }
#pragma unroll
  for (int m = 0; m < 4; ++m)
#pragma unroll
    for (int nfl = 0; nfl < 2; ++nfl) {
      const int col = w * 32 + nfl * 16 + ar;
      const float bv = bh[(t * 2 + 1) * 128 + col];
#pragma unroll
      for (int q = 0; q < 4; ++q) {
        const int r = rblk + m * 16 + g * 4 + q;
        H3[((size_t)t * nrows + r) * 128 + col] = f2bf(fmaxf(acc[m][nfl][q] + bv, 0.f));
      }
    }
}

// ---- K3: L4 + tail per 64-row block, all 3 towers; Wout dbuf 32KB chunks ----
__global__ __launch_bounds__(256, 2) void k_l4tail(
    const short* __restrict__ H3, const float* __restrict__ bout,
    const short* __restrict__ wp, const float* __restrict__ ti,
    const int* __restrict__ user, const int* __restrict__ item,
    float* __restrict__ out, int nrows) {
  __shared__ __align__(16) char WB[2][32768];
  __shared__ float sL[3][64];
  __shared__ float sS[3][64];
  __shared__ int sUid[64];
  __shared__ int sItm[64];
  const int tid = threadIdx.x, w = tid >> 6, lane = tid & 63;
  const int ar = lane & 15, g = lane >> 4;
  const int rblk = blockIdx.x * 64;
  const f32x4 fz = {0.f, 0.f, 0.f, 0.f};

  if (tid < 64) {
    sUid[tid] = user[rblk + tid];
    sItm[tid] = item[rblk + tid];
  }
  if (tid < 192) { (&sL[0][0])[tid] = 0.f; (&sS[0][0])[tid] = 0.f; }
  stageN(wp, WB[0], 384, tid, 8);  // tower0, K0 {0,1}
  __syncthreads();
  int cur = 0;

  for (int t = 0; t < 3; ++t) {
    f32x4 acc4[4][4];
#pragma unroll
    for (int m = 0; m < 4; ++m)
#pragma unroll
      for (int n = 0; n < 4; ++n) acc4[m][n] = fz;

    for (int half = 0; half < 2; ++half) {
      const int phase = t * 2 + half;
      if (phase < 5) stageN(wp, WB[cur ^ 1], 384 + (phase + 1) * 32, tid, 8);
      const char* wb = WB[cur];
#pragma unroll
      for (int k2 = 0; k2 < 2; ++k2) {
        const int K0 = half * 2 + k2;
        short8 a[4];
#pragma unroll
        for (int m = 0; m < 4; ++m)
          a[m] = *(const short8*)(H3 + ((size_t)t * nrows + rblk + m * 16 + ar) * 128 + K0 * 32 + g * 8);
#pragma unroll
        for (int nfl = 0; nfl < 4; ++nfl) {
          const short8 b = *(const short8*)(wb + (k2 * 16 + w * 4 + nfl) * 1024 + lane * 16);
#pragma unroll
          for (int m = 0; m < 4; ++m)
            acc4[m][nfl] = __builtin_amdgcn_mfma_f32_16x16x32_bf16(a[m], b, acc4[m][nfl], 0, 0, 0);
        }
      }

      if (half == 1) {
        // tail: fp32 logits/scores straight from acc4 (proven numerics)
        float pl[16], ps[16];
#pragma unroll
        for (int i = 0; i < 16; ++i) { pl[i] = 0.f; ps[i] = 0.f; }
#pragma unroll
        for (int m = 0; m < 4; ++m)
#pragma unroll
          for (int nfl = 0; nfl < 4; ++nfl) {
            const int col = w * 64 + nfl * 16 + ar;
            const float bo = bout[t * 256 + col];
#pragma unroll
            for (int q = 0; q < 4; ++q) {
              const int r = m * 16 + g * 4 + q;
              const float x = acc4[m][nfl][q] + bo;
              pl[m * 4 + q] += x * ti[(size_t)sUid[r] * 256 + col];
              ps[m * 4 + q] += x * ti[(size_t)sItm[r] * 256 + col];
            }
          }
#pragma unroll
        for (int i = 0; i < 16; ++i) {
          float a0 = pl[i], b0 = ps[i];
#pragma unroll
          for (int off = 1; off < 16; off <<= 1) {
            a0 += __shfl_xor(a0, off);
            b0 += __shfl_xor(b0, off);
          }
          pl[i] = a0; ps[i] = b0;
        }
        if (ar == 0) {
#pragma unroll
          for (int m = 0; m < 4; ++m)
#pragma unroll
            for (int q = 0; q < 4; ++q) {
              const int r = m * 16 + g * 4 + q;
              atomicAdd(&sL[t][r], pl[m * 4 + q]);
              atomicAdd(&sS[t][r], ps[m * 4 + q]);
            }
        }
      }
      __syncthreads();
      cur ^= 1;
    }
  }

  if (tid < 64) {
    const float l0 = sL[0][tid], l1 = sL[1][tid], l2 = sL[2][tid];
    const float mx = fmaxf(l0, fmaxf(l1, l2));
    const float e0 = __expf(l0 - mx), e1 = __expf(l1 - mx), e2 = __expf(l2 - mx);
    out[rblk + tid] =
        (e0 * sS[0][tid] + e1 * sS[1][tid] + e2 * sS[2][tid]) / (e0 + e1 + e2);
  }
}

extern "C" void kernel_launch(void* const* d_in, const int* in_sizes, int n_in,
                              void* d_out, int out_size, void* d_ws, size_t ws_size,
                              hipStream_t stream) {
  const int* user = (const int*)d_in[0];
  const int* item = (const int*)d_in[1];
  const float* su = (const float*)d_in[2];
  const float* ti = (const float*)d_in[3];
  const float* Win = (const float*)d_in[4];
  const float* bin = (const float*)d_in[5];
  const float* Wh = (const float*)d_in[6];
  const float* bh = (const float*)d_in[7];
  const float* Wout = (const float*)d_in[8];
  const float* bout = (const float*)d_in[9];
  float* out = (float*)d_out;
  char* ws = (char*)d_ws;

  const size_t WOFF = 1179648;  // packed weights: 294912 shorts
  short* wpk = (short*)ws;
  hipLaunchKernelGGL(pack_weights, dim3(144), dim3(256), 0, stream, Win, Wh, Wout, wpk);

  // chunk rows to fit workspace: 2048 B/row (U 512 + H1 768 + H3 768)
  size_t avail = (ws_size > WOFF) ? (ws_size - WOFF) : 0;
  long rpc = (long)((avail / 2048) & ~(size_t)127);
  if (rpc > 65536) rpc = 65536;
  if (rpc < 128) rpc = 128;  // minimal footprint fallback

  short* U = (short*)(ws + WOFF);
  short* H1 = (short*)(ws + WOFF + (size_t)rpc * 512);
  short* H3 = (short*)(ws + WOFF + (size_t)rpc * 512 + (size_t)rpc * 768);

  for (long r0 = 0; r0 < 65536; r0 += rpc) {
    const int nr = (int)((65536 - r0 < rpc) ? (65536 - r0) : rpc);
    hipLaunchKernelGGL(k_gather_u, dim3(nr / 8), dim3(256), 0, stream,
                       user + r0, su, U, nr);
    hipLaunchKernelGGL(k_l1, dim3(nr / 128, 3), dim3(256), 0, stream,
                       U, bin, wpk, H1, nr);
    hipLaunchKernelGGL(k_l23, dim3(nr / 64, 3), dim3(256), 0, stream,
                       H1, bh, wpk, H3, nr);
    hipLaunchKernelGGL(k_l4tail, dim3(nr / 64), dim3(256), 0, stream,
                       H3, bout, wpk, ti, user + r0, item + r0, out + r0, nr);
  }
}